// Round 1
// baseline (1099.483 us; speedup 1.0000x reference)
//
#include <hip/hip_runtime.h>

// ---------------------------------------------------------------------------
// GINE x2 + mean-pool + FC.  fp32 end-to-end baseline.
// Phases:
//   memset agg1, agg2
//   conv1_edge : thread/edge, 7ch, atomicAdd -> agg1[dst]   (stride 8, padded)
//   mlp1       : 64 lanes/node, W1a/W1b in LDS -> h1
//   conv2_edge : 64 lanes/edge (lane=channel), atomicAdd -> agg2[dst]
//   mlp2       : 64 lanes/node, W2a/W2b in LDS -> h2
//   pool_fc    : block/graph, binary-search sorted batch, mean, @Wfc+bfc
// ---------------------------------------------------------------------------

__global__ __launch_bounds__(256) void conv1_edge_kernel(
    const float* __restrict__ x, const float* __restrict__ ea,
    const float* __restrict__ We1, const float* __restrict__ be1,
    const int* __restrict__ srcIdx, const int* __restrict__ dstIdx,
    float* __restrict__ agg1, int E) {
  int e = blockIdx.x * blockDim.x + threadIdx.x;
  if (e >= E) return;
  float4 a = reinterpret_cast<const float4*>(ea)[e];
  int s = srcIdx[e], d = dstIdx[e];
  const float* xs = x + (size_t)s * 7;
#pragma unroll
  for (int c = 0; c < 7; ++c) {
    float v = be1[c] + a.x * We1[c] + a.y * We1[7 + c] + a.z * We1[14 + c] +
              a.w * We1[21 + c];
    v += xs[c];
    v = fmaxf(v, 0.f);
    atomicAdd(&agg1[(size_t)d * 8 + c], v);
  }
}

__global__ __launch_bounds__(256) void mlp1_kernel(
    const float* __restrict__ x, const float* __restrict__ agg1,
    const float* __restrict__ W1a, const float* __restrict__ b1a,
    const float* __restrict__ W1b, const float* __restrict__ b1b,
    float* __restrict__ h1, int N) {
  __shared__ float sWa[7 * 64];
  __shared__ float sWb[64 * 64];
  __shared__ float sba[64], sbb[64];
  __shared__ float sp[4][8];
  __shared__ float st[4][64];
  for (int i = threadIdx.x; i < 7 * 64; i += 256) sWa[i] = W1a[i];
  for (int i = threadIdx.x; i < 64 * 64; i += 256) sWb[i] = W1b[i];
  if (threadIdx.x < 64) {
    sba[threadIdx.x] = b1a[threadIdx.x];
    sbb[threadIdx.x] = b1b[threadIdx.x];
  }
  __syncthreads();
  int g = threadIdx.x >> 6;
  int j = threadIdx.x & 63;
  int ngroups = (N + 3) >> 2;
  for (int grp = blockIdx.x; grp < ngroups; grp += gridDim.x) {
    int n = grp * 4 + g;
    if (n < N && j < 7) sp[g][j] = x[(size_t)n * 7 + j] + agg1[(size_t)n * 8 + j];
    __syncthreads();
    float t = 0.f;
    if (n < N) {
      t = sba[j];
#pragma unroll
      for (int k = 0; k < 7; ++k) t += sp[g][k] * sWa[k * 64 + j];
      t = fmaxf(t, 0.f);
      st[g][j] = t;
    }
    __syncthreads();
    if (n < N) {
      float h = sbb[j];
#pragma unroll
      for (int k = 0; k < 64; ++k) h += st[g][k] * sWb[k * 64 + j];
      h1[(size_t)n * 64 + j] = fmaxf(h, 0.f);
    }
    __syncthreads();
  }
}

__global__ __launch_bounds__(256) void conv2_edge_kernel(
    const float* __restrict__ h1, const float* __restrict__ ea,
    const float* __restrict__ We2, const float* __restrict__ be2,
    const int* __restrict__ srcIdx, const int* __restrict__ dstIdx,
    float* __restrict__ agg2, int E) {
  int e = blockIdx.x * 4 + (threadIdx.x >> 6);
  int j = threadIdx.x & 63;
  if (e >= E) return;
  float4 a = reinterpret_cast<const float4*>(ea)[e];
  int s = srcIdx[e], d = dstIdx[e];
  float v = be2[j] + a.x * We2[j] + a.y * We2[64 + j] + a.z * We2[128 + j] +
            a.w * We2[192 + j];
  v += h1[(size_t)s * 64 + j];
  v = fmaxf(v, 0.f);
  atomicAdd(&agg2[(size_t)d * 64 + j], v);
}

__global__ __launch_bounds__(256) void mlp2_kernel(
    const float* __restrict__ h1, const float* __restrict__ agg2,
    const float* __restrict__ W2a, const float* __restrict__ b2a,
    const float* __restrict__ W2b, const float* __restrict__ b2b,
    float* __restrict__ h2, int N) {
  __shared__ float sWa[64 * 64];
  __shared__ float sWb[64 * 64];
  __shared__ float sba[64], sbb[64];
  __shared__ float sp[4][64];
  __shared__ float st[4][64];
  for (int i = threadIdx.x; i < 64 * 64; i += 256) {
    sWa[i] = W2a[i];
    sWb[i] = W2b[i];
  }
  if (threadIdx.x < 64) {
    sba[threadIdx.x] = b2a[threadIdx.x];
    sbb[threadIdx.x] = b2b[threadIdx.x];
  }
  __syncthreads();
  int g = threadIdx.x >> 6;
  int j = threadIdx.x & 63;
  int ngroups = (N + 3) >> 2;
  for (int grp = blockIdx.x; grp < ngroups; grp += gridDim.x) {
    int n = grp * 4 + g;
    if (n < N)
      sp[g][j] = h1[(size_t)n * 64 + j] + agg2[(size_t)n * 64 + j];
    __syncthreads();
    if (n < N) {
      float t = sba[j];
#pragma unroll
      for (int k = 0; k < 64; ++k) t += sp[g][k] * sWa[k * 64 + j];
      t = fmaxf(t, 0.f);
      st[g][j] = t;
    }
    __syncthreads();
    if (n < N) {
      float h = sbb[j];
#pragma unroll
      for (int k = 0; k < 64; ++k) h += st[g][k] * sWb[k * 64 + j];
      h2[(size_t)n * 64 + j] = fmaxf(h, 0.f);
    }
    __syncthreads();
  }
}

__global__ __launch_bounds__(64) void pool_fc_kernel(
    const float* __restrict__ h2, const int* __restrict__ batch,
    const float* __restrict__ Wfc, const float* __restrict__ bfc,
    float* __restrict__ out, int N, int G) {
  int g = blockIdx.x;
  int j = threadIdx.x;  // 0..63
  // lower_bound(batch, g) and lower_bound(batch, g+1) on sorted batch
  int lo = 0, hi = N;
  while (lo < hi) {
    int mid = (lo + hi) >> 1;
    if (batch[mid] < g) lo = mid + 1; else hi = mid;
  }
  int start = lo;
  lo = start; hi = N;
  while (lo < hi) {
    int mid = (lo + hi) >> 1;
    if (batch[mid] < g + 1) lo = mid + 1; else hi = mid;
  }
  int end = lo;
  float s = 0.f;
  for (int r = start; r < end; ++r) s += h2[(size_t)r * 64 + j];
  float cnt = (float)(end - start);
  float pooled = s / fmaxf(cnt, 1.f);
  __shared__ float spool[64];
  spool[j] = pooled;
  __syncthreads();
  if (j < 12) {
    float o = bfc[j];
#pragma unroll
    for (int k = 0; k < 64; ++k) o += spool[k] * Wfc[k * 12 + j];
    out[(size_t)g * 12 + j] = o;
  }
}

extern "C" void kernel_launch(void* const* d_in, const int* in_sizes, int n_in,
                              void* d_out, int out_size, void* d_ws,
                              size_t ws_size, hipStream_t stream) {
  const float* x   = (const float*)d_in[0];
  const float* ea  = (const float*)d_in[1];
  const float* We1 = (const float*)d_in[2];
  const float* be1 = (const float*)d_in[3];
  const float* We2 = (const float*)d_in[4];
  const float* be2 = (const float*)d_in[5];
  const float* W1a = (const float*)d_in[6];
  const float* b1a = (const float*)d_in[7];
  const float* W1b = (const float*)d_in[8];
  const float* b1b = (const float*)d_in[9];
  const float* W2a = (const float*)d_in[10];
  const float* b2a = (const float*)d_in[11];
  const float* W2b = (const float*)d_in[12];
  const float* b2b = (const float*)d_in[13];
  const float* Wfc = (const float*)d_in[14];
  const float* bfc = (const float*)d_in[15];
  const int* eidx  = (const int*)d_in[16];
  const int* batch = (const int*)d_in[17];

  int N = in_sizes[0] / 7;
  int E = in_sizes[1] / 4;
  int G = out_size / 12;
  const int* srcIdx = eidx;
  const int* dstIdx = eidx + E;

  float* ws   = (float*)d_ws;
  float* agg1 = ws;                          // N*8 (stride-8 padded)
  float* h1   = agg1 + (size_t)N * 8;        // N*64
  float* agg2 = h1 + (size_t)N * 64;         // N*64
  float* h2   = agg2 + (size_t)N * 64;       // N*64
  // total = N*(8+64*3) floats = 80 MB at N=100000

  hipMemsetAsync(agg1, 0, (size_t)N * 8 * sizeof(float), stream);
  hipMemsetAsync(agg2, 0, (size_t)N * 64 * sizeof(float), stream);

  conv1_edge_kernel<<<(E + 255) / 256, 256, 0, stream>>>(x, ea, We1, be1,
                                                         srcIdx, dstIdx, agg1, E);
  mlp1_kernel<<<2048, 256, 0, stream>>>(x, agg1, W1a, b1a, W1b, b1b, h1, N);
  conv2_edge_kernel<<<(E + 3) / 4, 256, 0, stream>>>(h1, ea, We2, be2, srcIdx,
                                                     dstIdx, agg2, E);
  mlp2_kernel<<<2048, 256, 0, stream>>>(h1, agg2, W2a, b2a, W2b, b2b, h2, N);
  pool_fc_kernel<<<G, 64, 0, stream>>>(h2, batch, Wfc, bfc, (float*)d_out, N, G);
}

// Round 2
// 693.128 us; speedup vs baseline: 1.5863x; 1.5863x over previous
//
#include <hip/hip_runtime.h>

// ---------------------------------------------------------------------------
// GINE x2 + mean-pool + FC.  fp32, CSR-gather (no float atomics).
// Phases:
//   memset deg
//   hist      : thread/edge atomicAdd(deg[dst],1)           (int, 1.6M)
//   scan1/2/3 : exclusive scan deg -> cursor (=rowstart)
//   scatter   : pos=atomicAdd(cursor[dst]); csr[pos]={src,eid}
//               (after scatter, cursor[n] == row end; start = end-deg[n])
//   conv1_gather : thread/node, 7ch gather-accumulate -> agg1 (stride 8)
//   mlp1      : wave/node, W1a/W1b in LDS -> h1
//   conv2_mlp2: wave/node, lane=channel gather of h1[src] (256B coalesced),
//               fused with MLP2 in LDS -> h2  (no agg2 round-trip)
//   pool_fc   : block/graph, binary-search sorted batch, mean, @Wfc+bfc
// ---------------------------------------------------------------------------

#define CHUNK 1024

__global__ __launch_bounds__(256) void hist_kernel(
    const int* __restrict__ dstIdx, int* __restrict__ deg, int E) {
  int e = blockIdx.x * 256 + threadIdx.x;
  if (e < E) atomicAdd(&deg[dstIdx[e]], 1);
}

__global__ __launch_bounds__(256) void scan1_kernel(
    const int* __restrict__ deg, int* __restrict__ cursor,
    int* __restrict__ blockSum, int N) {
  __shared__ int sd[256];
  int t = threadIdx.x;
  int base = blockIdx.x * CHUNK + t * 4;
  int v0 = (base + 0 < N) ? deg[base + 0] : 0;
  int v1 = (base + 1 < N) ? deg[base + 1] : 0;
  int v2 = (base + 2 < N) ? deg[base + 2] : 0;
  int v3 = (base + 3 < N) ? deg[base + 3] : 0;
  int ts = v0 + v1 + v2 + v3;
  sd[t] = ts;
  __syncthreads();
  for (int off = 1; off < 256; off <<= 1) {
    int xv = (t >= off) ? sd[t - off] : 0;
    __syncthreads();
    sd[t] += xv;
    __syncthreads();
  }
  int excl = sd[t] - ts;
  if (t == 255) blockSum[blockIdx.x] = sd[255];
  if (base + 0 < N) cursor[base + 0] = excl;
  if (base + 1 < N) cursor[base + 1] = excl + v0;
  if (base + 2 < N) cursor[base + 2] = excl + v0 + v1;
  if (base + 3 < N) cursor[base + 3] = excl + v0 + v1 + v2;
}

__global__ void scan2_kernel(const int* __restrict__ blockSum,
                             int* __restrict__ blockOff, int nb) {
  if (threadIdx.x == 0) {
    int run = 0;
    for (int i = 0; i < nb; ++i) {
      blockOff[i] = run;
      run += blockSum[i];
    }
  }
}

__global__ __launch_bounds__(256) void scan3_kernel(
    int* __restrict__ cursor, const int* __restrict__ blockOff, int N) {
  int i = blockIdx.x * 256 + threadIdx.x;
  if (i < N) cursor[i] += blockOff[i >> 10];  // log2(CHUNK)
}

__global__ __launch_bounds__(256) void scatter_kernel(
    const int* __restrict__ srcIdx, const int* __restrict__ dstIdx,
    int* __restrict__ cursor, int2* __restrict__ csr, int E) {
  int e = blockIdx.x * 256 + threadIdx.x;
  if (e >= E) return;
  int pos = atomicAdd(&cursor[dstIdx[e]], 1);
  csr[pos] = make_int2(srcIdx[e], e);
}

__global__ __launch_bounds__(256) void conv1_gather_kernel(
    const float* __restrict__ x, const float* __restrict__ ea,
    const float* __restrict__ We1, const float* __restrict__ be1,
    const int* __restrict__ deg, const int* __restrict__ cursor,
    const int2* __restrict__ csr, float* __restrict__ agg1, int N) {
  int n = blockIdx.x * 256 + threadIdx.x;
  if (n >= N) return;
  float w[28], b[7];
#pragma unroll
  for (int i = 0; i < 28; ++i) w[i] = We1[i];
#pragma unroll
  for (int i = 0; i < 7; ++i) b[i] = be1[i];
  int end = cursor[n];
  int start = end - deg[n];
  float acc[7];
#pragma unroll
  for (int c = 0; c < 7; ++c) acc[c] = 0.f;
  for (int i = start; i < end; ++i) {
    int2 se = csr[i];
    float4 a = reinterpret_cast<const float4*>(ea)[se.y];
    const float* xs = x + (size_t)se.x * 7;
#pragma unroll
    for (int c = 0; c < 7; ++c) {
      float v = b[c] + a.x * w[c] + a.y * w[7 + c] + a.z * w[14 + c] +
                a.w * w[21 + c] + xs[c];
      acc[c] += fmaxf(v, 0.f);
    }
  }
#pragma unroll
  for (int c = 0; c < 7; ++c) agg1[(size_t)n * 8 + c] = acc[c];
}

__global__ __launch_bounds__(256) void mlp1_kernel(
    const float* __restrict__ x, const float* __restrict__ agg1,
    const float* __restrict__ W1a, const float* __restrict__ b1a,
    const float* __restrict__ W1b, const float* __restrict__ b1b,
    float* __restrict__ h1, int N) {
  __shared__ float sWa[7 * 64];
  __shared__ float sWb[64 * 64];
  __shared__ float sba[64], sbb[64];
  __shared__ float sp[4][8];
  __shared__ float st[4][64];
  for (int i = threadIdx.x; i < 7 * 64; i += 256) sWa[i] = W1a[i];
  for (int i = threadIdx.x; i < 64 * 64; i += 256) sWb[i] = W1b[i];
  if (threadIdx.x < 64) {
    sba[threadIdx.x] = b1a[threadIdx.x];
    sbb[threadIdx.x] = b1b[threadIdx.x];
  }
  __syncthreads();
  int g = threadIdx.x >> 6;
  int j = threadIdx.x & 63;
  int ngroups = (N + 3) >> 2;
  for (int grp = blockIdx.x; grp < ngroups; grp += gridDim.x) {
    int n = grp * 4 + g;
    if (n < N && j < 7) sp[g][j] = x[(size_t)n * 7 + j] + agg1[(size_t)n * 8 + j];
    __syncthreads();
    if (n < N) {
      float t = sba[j];
#pragma unroll
      for (int k = 0; k < 7; ++k) t += sp[g][k] * sWa[k * 64 + j];
      st[g][j] = fmaxf(t, 0.f);
    }
    __syncthreads();
    if (n < N) {
      float h = sbb[j];
#pragma unroll
      for (int k = 0; k < 64; ++k) h += st[g][k] * sWb[k * 64 + j];
      h1[(size_t)n * 64 + j] = fmaxf(h, 0.f);
    }
    __syncthreads();
  }
}

__global__ __launch_bounds__(256) void conv2_mlp2_kernel(
    const float* __restrict__ h1, const float* __restrict__ ea,
    const int2* __restrict__ csr, const int* __restrict__ deg,
    const int* __restrict__ cursor, const float* __restrict__ We2,
    const float* __restrict__ be2, const float* __restrict__ W2a,
    const float* __restrict__ b2a, const float* __restrict__ W2b,
    const float* __restrict__ b2b, float* __restrict__ h2, int N) {
  __shared__ float sWa[64 * 64];
  __shared__ float sWb[64 * 64];
  __shared__ float sba[64], sbb[64];
  __shared__ float sp[4][64];
  __shared__ float st[4][64];
  for (int i = threadIdx.x; i < 64 * 64; i += 256) {
    sWa[i] = W2a[i];
    sWb[i] = W2b[i];
  }
  if (threadIdx.x < 64) {
    sba[threadIdx.x] = b2a[threadIdx.x];
    sbb[threadIdx.x] = b2b[threadIdx.x];
  }
  int g = threadIdx.x >> 6;
  int j = threadIdx.x & 63;
  float w0 = We2[j], w1 = We2[64 + j], w2 = We2[128 + j], w3 = We2[192 + j];
  float bej = be2[j];
  __syncthreads();
  int ngroups = (N + 3) >> 2;
  for (int grp = blockIdx.x; grp < ngroups; grp += gridDim.x) {
    int n = grp * 4 + g;
    if (n < N) {
      int end = cursor[n];
      int start = end - deg[n];
      float acc = 0.f;
      for (int i = start; i < end; ++i) {
        int2 se = csr[i];
        int srcn = __builtin_amdgcn_readfirstlane(se.x);
        int eid = __builtin_amdgcn_readfirstlane(se.y);
        float4 a = reinterpret_cast<const float4*>(ea)[eid];
        float e2 = bej + a.x * w0 + a.y * w1 + a.z * w2 + a.w * w3;
        acc += fmaxf(h1[(size_t)srcn * 64 + j] + e2, 0.f);
      }
      sp[g][j] = h1[(size_t)n * 64 + j] + acc;
    }
    __syncthreads();
    if (n < N) {
      float t = sba[j];
#pragma unroll
      for (int k = 0; k < 64; ++k) t += sp[g][k] * sWa[k * 64 + j];
      st[g][j] = fmaxf(t, 0.f);
    }
    __syncthreads();
    if (n < N) {
      float h = sbb[j];
#pragma unroll
      for (int k = 0; k < 64; ++k) h += st[g][k] * sWb[k * 64 + j];
      h2[(size_t)n * 64 + j] = fmaxf(h, 0.f);
    }
    __syncthreads();
  }
}

__global__ __launch_bounds__(64) void pool_fc_kernel(
    const float* __restrict__ h2, const int* __restrict__ batch,
    const float* __restrict__ Wfc, const float* __restrict__ bfc,
    float* __restrict__ out, int N, int G) {
  int g = blockIdx.x;
  int j = threadIdx.x;  // 0..63
  int lo = 0, hi = N;
  while (lo < hi) {
    int mid = (lo + hi) >> 1;
    if (batch[mid] < g) lo = mid + 1; else hi = mid;
  }
  int start = lo;
  lo = start; hi = N;
  while (lo < hi) {
    int mid = (lo + hi) >> 1;
    if (batch[mid] < g + 1) lo = mid + 1; else hi = mid;
  }
  int end = lo;
  float s = 0.f;
  for (int r = start; r < end; ++r) s += h2[(size_t)r * 64 + j];
  float cnt = (float)(end - start);
  float pooled = s / fmaxf(cnt, 1.f);
  __shared__ float spool[64];
  spool[j] = pooled;
  __syncthreads();
  if (j < 12) {
    float o = bfc[j];
#pragma unroll
    for (int k = 0; k < 64; ++k) o += spool[k] * Wfc[k * 12 + j];
    out[(size_t)g * 12 + j] = o;
  }
}

extern "C" void kernel_launch(void* const* d_in, const int* in_sizes, int n_in,
                              void* d_out, int out_size, void* d_ws,
                              size_t ws_size, hipStream_t stream) {
  const float* x   = (const float*)d_in[0];
  const float* ea  = (const float*)d_in[1];
  const float* We1 = (const float*)d_in[2];
  const float* be1 = (const float*)d_in[3];
  const float* We2 = (const float*)d_in[4];
  const float* be2 = (const float*)d_in[5];
  const float* W1a = (const float*)d_in[6];
  const float* b1a = (const float*)d_in[7];
  const float* W1b = (const float*)d_in[8];
  const float* b1b = (const float*)d_in[9];
  const float* W2a = (const float*)d_in[10];
  const float* b2a = (const float*)d_in[11];
  const float* W2b = (const float*)d_in[12];
  const float* b2b = (const float*)d_in[13];
  const float* Wfc = (const float*)d_in[14];
  const float* bfc = (const float*)d_in[15];
  const int* eidx  = (const int*)d_in[16];
  const int* batch = (const int*)d_in[17];

  int N = in_sizes[0] / 7;
  int E = in_sizes[1] / 4;
  int G = out_size / 12;
  const int* srcIdx = eidx;
  const int* dstIdx = eidx + E;

  char* ws = (char*)d_ws;
  int*  deg      = (int*)ws;                         ws += (size_t)N * 4;
  int*  cursor   = (int*)ws;                         ws += (size_t)N * 4;
  int*  blockSum = (int*)ws;                         ws += 512;
  int*  blockOff = (int*)ws;                         ws += 512;
  int2* csr      = (int2*)ws;                        ws += (size_t)E * 8;
  float* agg1    = (float*)ws;                       ws += (size_t)N * 8 * 4;
  float* h1      = (float*)ws;                       ws += (size_t)N * 64 * 4;
  float* h2      = (float*)ws;                       /* += N*64*4 */
  // total ~68 MB

  int nb = (N + CHUNK - 1) / CHUNK;

  hipMemsetAsync(deg, 0, (size_t)N * 4, stream);
  hist_kernel<<<(E + 255) / 256, 256, 0, stream>>>(dstIdx, deg, E);
  scan1_kernel<<<nb, 256, 0, stream>>>(deg, cursor, blockSum, N);
  scan2_kernel<<<1, 64, 0, stream>>>(blockSum, blockOff, nb);
  scan3_kernel<<<(N + 255) / 256, 256, 0, stream>>>(cursor, blockOff, N);
  scatter_kernel<<<(E + 255) / 256, 256, 0, stream>>>(srcIdx, dstIdx, cursor,
                                                      csr, E);
  conv1_gather_kernel<<<(N + 255) / 256, 256, 0, stream>>>(
      x, ea, We1, be1, deg, cursor, csr, agg1, N);
  mlp1_kernel<<<2048, 256, 0, stream>>>(x, agg1, W1a, b1a, W1b, b1b, h1, N);
  conv2_mlp2_kernel<<<2048, 256, 0, stream>>>(h1, ea, csr, deg, cursor, We2,
                                              be2, W2a, b2a, W2b, b2b, h2, N);
  pool_fc_kernel<<<G, 64, 0, stream>>>(h2, batch, Wfc, bfc, (float*)d_out, N, G);
}

// Round 3
// 503.464 us; speedup vs baseline: 2.1838x; 1.3767x over previous
//
#include <hip/hip_runtime.h>
#include <hip/hip_bf16.h>

// ---------------------------------------------------------------------------
// GINE x2 + mean-pool + FC.  CSR-gather, ea reordered into CSR order,
// h1 stored bf16 to halve the conv2 gather traffic.
// Phases:
//   memset deg
//   hist       : thread/edge atomicAdd(deg[dst],1)        (int)
//   scan1/2/3  : exclusive scan deg -> cursor (row starts)
//   scatter    : pos=atomicAdd(cursor[dst]); csr_src[pos]=src;
//                csr_ea[pos]=ea[e]  (16B, so convs read ea sequentially)
//                (after scatter, cursor[n] == row end)
//   conv1_gather : thread/node, x[src] gather (x=2.8MB, L2-resident) -> agg1
//   mlp1       : wave/node, W in LDS -> h1 (bf16, RNE)
//   conv2_mlp2 : wave/node, lane=channel; lane-parallel {src,ea} prefetch,
//                shfl broadcast, unroll-4 bf16 gathers; fused MLP2 -> h2
//   pool_fc    : block/graph, binary-search sorted batch, mean, @Wfc+bfc
// ---------------------------------------------------------------------------

#define CHUNK 1024

__global__ __launch_bounds__(256) void hist_kernel(
    const int* __restrict__ dstIdx, int* __restrict__ deg, int E) {
  int e = blockIdx.x * 256 + threadIdx.x;
  if (e < E) atomicAdd(&deg[dstIdx[e]], 1);
}

__global__ __launch_bounds__(256) void scan1_kernel(
    const int* __restrict__ deg, int* __restrict__ cursor,
    int* __restrict__ blockSum, int N) {
  __shared__ int sd[256];
  int t = threadIdx.x;
  int base = blockIdx.x * CHUNK + t * 4;
  int v0 = (base + 0 < N) ? deg[base + 0] : 0;
  int v1 = (base + 1 < N) ? deg[base + 1] : 0;
  int v2 = (base + 2 < N) ? deg[base + 2] : 0;
  int v3 = (base + 3 < N) ? deg[base + 3] : 0;
  int ts = v0 + v1 + v2 + v3;
  sd[t] = ts;
  __syncthreads();
  for (int off = 1; off < 256; off <<= 1) {
    int xv = (t >= off) ? sd[t - off] : 0;
    __syncthreads();
    sd[t] += xv;
    __syncthreads();
  }
  int excl = sd[t] - ts;
  if (t == 255) blockSum[blockIdx.x] = sd[255];
  if (base + 0 < N) cursor[base + 0] = excl;
  if (base + 1 < N) cursor[base + 1] = excl + v0;
  if (base + 2 < N) cursor[base + 2] = excl + v0 + v1;
  if (base + 3 < N) cursor[base + 3] = excl + v0 + v1 + v2;
}

__global__ void scan2_kernel(const int* __restrict__ blockSum,
                             int* __restrict__ blockOff, int nb) {
  if (threadIdx.x == 0) {
    int run = 0;
    for (int i = 0; i < nb; ++i) {
      blockOff[i] = run;
      run += blockSum[i];
    }
  }
}

__global__ __launch_bounds__(256) void scan3_kernel(
    int* __restrict__ cursor, const int* __restrict__ blockOff, int N) {
  int i = blockIdx.x * 256 + threadIdx.x;
  if (i < N) cursor[i] += blockOff[i >> 10];  // log2(CHUNK)
}

__global__ __launch_bounds__(256) void scatter_kernel(
    const int* __restrict__ srcIdx, const int* __restrict__ dstIdx,
    const float* __restrict__ ea, int* __restrict__ cursor,
    int* __restrict__ csr_src, float4* __restrict__ csr_ea, int E) {
  int e = blockIdx.x * 256 + threadIdx.x;
  if (e >= E) return;
  float4 a = reinterpret_cast<const float4*>(ea)[e];  // sequential, coalesced
  int pos = atomicAdd(&cursor[dstIdx[e]], 1);
  csr_src[pos] = srcIdx[e];
  csr_ea[pos] = a;
}

__global__ __launch_bounds__(256) void conv1_gather_kernel(
    const float* __restrict__ x, const float4* __restrict__ csr_ea,
    const int* __restrict__ csr_src, const float* __restrict__ We1,
    const float* __restrict__ be1, const int* __restrict__ deg,
    const int* __restrict__ cursor, float* __restrict__ agg1, int N) {
  int n = blockIdx.x * 256 + threadIdx.x;
  if (n >= N) return;
  float w[28], b[7];
#pragma unroll
  for (int i = 0; i < 28; ++i) w[i] = We1[i];
#pragma unroll
  for (int i = 0; i < 7; ++i) b[i] = be1[i];
  int end = cursor[n];
  int start = end - deg[n];
  float acc[7];
#pragma unroll
  for (int c = 0; c < 7; ++c) acc[c] = 0.f;
  for (int i = start; i < end; ++i) {
    int s = csr_src[i];          // sequential
    float4 a = csr_ea[i];        // sequential
    const float* xs = x + (size_t)s * 7;  // random but x is 2.8MB -> L2
#pragma unroll
    for (int c = 0; c < 7; ++c) {
      float v = b[c] + a.x * w[c] + a.y * w[7 + c] + a.z * w[14 + c] +
                a.w * w[21 + c] + xs[c];
      acc[c] += fmaxf(v, 0.f);
    }
  }
#pragma unroll
  for (int c = 0; c < 7; ++c) agg1[(size_t)n * 8 + c] = acc[c];
}

__global__ __launch_bounds__(256) void mlp1_kernel(
    const float* __restrict__ x, const float* __restrict__ agg1,
    const float* __restrict__ W1a, const float* __restrict__ b1a,
    const float* __restrict__ W1b, const float* __restrict__ b1b,
    ushort* __restrict__ h1b, int N) {
  __shared__ float sWa[7 * 64];
  __shared__ float sWb[64 * 64];
  __shared__ float sba[64], sbb[64];
  __shared__ float sp[4][8];
  __shared__ float st[4][64];
  for (int i = threadIdx.x; i < 7 * 64; i += 256) sWa[i] = W1a[i];
  for (int i = threadIdx.x; i < 64 * 64; i += 256) sWb[i] = W1b[i];
  if (threadIdx.x < 64) {
    sba[threadIdx.x] = b1a[threadIdx.x];
    sbb[threadIdx.x] = b1b[threadIdx.x];
  }
  __syncthreads();
  int g = threadIdx.x >> 6;
  int j = threadIdx.x & 63;
  int ngroups = (N + 3) >> 2;
  for (int grp = blockIdx.x; grp < ngroups; grp += gridDim.x) {
    int n = grp * 4 + g;
    if (n < N && j < 7) sp[g][j] = x[(size_t)n * 7 + j] + agg1[(size_t)n * 8 + j];
    __syncthreads();
    if (n < N) {
      float t = sba[j];
#pragma unroll
      for (int k = 0; k < 7; ++k) t += sp[g][k] * sWa[k * 64 + j];
      st[g][j] = fmaxf(t, 0.f);
    }
    __syncthreads();
    if (n < N) {
      float h = sbb[j];
#pragma unroll
      for (int k = 0; k < 64; ++k) h += st[g][k] * sWb[k * 64 + j];
      h = fmaxf(h, 0.f);
      __hip_bfloat16 hb = __float2bfloat16(h);  // RNE
      h1b[(size_t)n * 64 + j] = *reinterpret_cast<ushort*>(&hb);
    }
    __syncthreads();
  }
}

__device__ __forceinline__ float bf2f(ushort u) {
  return __uint_as_float(((unsigned)u) << 16);
}

__global__ __launch_bounds__(256) void conv2_mlp2_kernel(
    const ushort* __restrict__ h1b, const float4* __restrict__ csr_ea,
    const int* __restrict__ csr_src, const int* __restrict__ deg,
    const int* __restrict__ cursor, const float* __restrict__ We2,
    const float* __restrict__ be2, const float* __restrict__ W2a,
    const float* __restrict__ b2a, const float* __restrict__ W2b,
    const float* __restrict__ b2b, float* __restrict__ h2, int N) {
  __shared__ float sWa[64 * 64];
  __shared__ float sWb[64 * 64];
  __shared__ float sba[64], sbb[64];
  __shared__ float sp[4][64];
  __shared__ float st[4][64];
  for (int i = threadIdx.x; i < 64 * 64; i += 256) {
    sWa[i] = W2a[i];
    sWb[i] = W2b[i];
  }
  if (threadIdx.x < 64) {
    sba[threadIdx.x] = b2a[threadIdx.x];
    sbb[threadIdx.x] = b2b[threadIdx.x];
  }
  int g = threadIdx.x >> 6;
  int j = threadIdx.x & 63;
  float w0 = We2[j], w1 = We2[64 + j], w2 = We2[128 + j], w3 = We2[192 + j];
  float bej = be2[j];
  __syncthreads();
  int ngroups = (N + 3) >> 2;
  for (int grp = blockIdx.x; grp < ngroups; grp += gridDim.x) {
    int n = grp * 4 + g;
    if (n < N) {
      int end = cursor[n];
      int start = end - deg[n];
      float acc0 = 0.f, acc1 = 0.f;
      for (int base = start; base < end; base += 64) {
        int cnt = min(64, end - base);
        int sl = 0;
        float4 al = make_float4(0.f, 0.f, 0.f, 0.f);
        if (base + j < end) {
          sl = csr_src[base + j];   // coalesced
          al = csr_ea[base + j];    // coalesced 16B
        }
        int i = 0;
        for (; i + 4 <= cnt; i += 4) {
          int s0 = __shfl(sl, i + 0), s1 = __shfl(sl, i + 1);
          int s2 = __shfl(sl, i + 2), s3 = __shfl(sl, i + 3);
          float e0 = bej + __shfl(al.x, i + 0) * w0 + __shfl(al.y, i + 0) * w1 +
                     __shfl(al.z, i + 0) * w2 + __shfl(al.w, i + 0) * w3;
          float e1 = bej + __shfl(al.x, i + 1) * w0 + __shfl(al.y, i + 1) * w1 +
                     __shfl(al.z, i + 1) * w2 + __shfl(al.w, i + 1) * w3;
          float e2 = bej + __shfl(al.x, i + 2) * w0 + __shfl(al.y, i + 2) * w1 +
                     __shfl(al.z, i + 2) * w2 + __shfl(al.w, i + 2) * w3;
          float e3 = bej + __shfl(al.x, i + 3) * w0 + __shfl(al.y, i + 3) * w1 +
                     __shfl(al.z, i + 3) * w2 + __shfl(al.w, i + 3) * w3;
          float v0 = bf2f(h1b[(size_t)s0 * 64 + j]);  // 4 independent gathers
          float v1 = bf2f(h1b[(size_t)s1 * 64 + j]);
          float v2 = bf2f(h1b[(size_t)s2 * 64 + j]);
          float v3 = bf2f(h1b[(size_t)s3 * 64 + j]);
          acc0 += fmaxf(v0 + e0, 0.f) + fmaxf(v2 + e2, 0.f);
          acc1 += fmaxf(v1 + e1, 0.f) + fmaxf(v3 + e3, 0.f);
        }
        for (; i < cnt; ++i) {
          int s0 = __shfl(sl, i);
          float e0 = bej + __shfl(al.x, i) * w0 + __shfl(al.y, i) * w1 +
                     __shfl(al.z, i) * w2 + __shfl(al.w, i) * w3;
          acc0 += fmaxf(bf2f(h1b[(size_t)s0 * 64 + j]) + e0, 0.f);
        }
      }
      float self = bf2f(h1b[(size_t)n * 64 + j]);
      sp[g][j] = self + acc0 + acc1;
    }
    __syncthreads();
    if (n < N) {
      float t = sba[j];
#pragma unroll
      for (int k = 0; k < 64; ++k) t += sp[g][k] * sWa[k * 64 + j];
      st[g][j] = fmaxf(t, 0.f);
    }
    __syncthreads();
    if (n < N) {
      float h = sbb[j];
#pragma unroll
      for (int k = 0; k < 64; ++k) h += st[g][k] * sWb[k * 64 + j];
      h2[(size_t)n * 64 + j] = fmaxf(h, 0.f);
    }
    __syncthreads();
  }
}

__global__ __launch_bounds__(64) void pool_fc_kernel(
    const float* __restrict__ h2, const int* __restrict__ batch,
    const float* __restrict__ Wfc, const float* __restrict__ bfc,
    float* __restrict__ out, int N, int G) {
  int g = blockIdx.x;
  int j = threadIdx.x;  // 0..63
  int lo = 0, hi = N;
  while (lo < hi) {
    int mid = (lo + hi) >> 1;
    if (batch[mid] < g) lo = mid + 1; else hi = mid;
  }
  int start = lo;
  lo = start; hi = N;
  while (lo < hi) {
    int mid = (lo + hi) >> 1;
    if (batch[mid] < g + 1) lo = mid + 1; else hi = mid;
  }
  int end = lo;
  float s = 0.f;
  for (int r = start; r < end; ++r) s += h2[(size_t)r * 64 + j];
  float cnt = (float)(end - start);
  float pooled = s / fmaxf(cnt, 1.f);
  __shared__ float spool[64];
  spool[j] = pooled;
  __syncthreads();
  if (j < 12) {
    float o = bfc[j];
#pragma unroll
    for (int k = 0; k < 64; ++k) o += spool[k] * Wfc[k * 12 + j];
    out[(size_t)g * 12 + j] = o;
  }
}

extern "C" void kernel_launch(void* const* d_in, const int* in_sizes, int n_in,
                              void* d_out, int out_size, void* d_ws,
                              size_t ws_size, hipStream_t stream) {
  const float* x   = (const float*)d_in[0];
  const float* ea  = (const float*)d_in[1];
  const float* We1 = (const float*)d_in[2];
  const float* be1 = (const float*)d_in[3];
  const float* We2 = (const float*)d_in[4];
  const float* be2 = (const float*)d_in[5];
  const float* W1a = (const float*)d_in[6];
  const float* b1a = (const float*)d_in[7];
  const float* W1b = (const float*)d_in[8];
  const float* b1b = (const float*)d_in[9];
  const float* W2a = (const float*)d_in[10];
  const float* b2a = (const float*)d_in[11];
  const float* W2b = (const float*)d_in[12];
  const float* b2b = (const float*)d_in[13];
  const float* Wfc = (const float*)d_in[14];
  const float* bfc = (const float*)d_in[15];
  const int* eidx  = (const int*)d_in[16];
  const int* batch = (const int*)d_in[17];

  int N = in_sizes[0] / 7;
  int E = in_sizes[1] / 4;
  int G = out_size / 12;
  const int* srcIdx = eidx;
  const int* dstIdx = eidx + E;

  char* ws = (char*)d_ws;
  int*    deg      = (int*)ws;      ws += (size_t)N * 4;
  int*    cursor   = (int*)ws;      ws += (size_t)N * 4;
  int*    blockSum = (int*)ws;      ws += 512;
  int*    blockOff = (int*)ws;      ws += 512;
  int*    csr_src  = (int*)ws;      ws += (size_t)E * 4;
  float4* csr_ea   = (float4*)ws;   ws += (size_t)E * 16;
  float*  agg1     = (float*)ws;    ws += (size_t)N * 8 * 4;
  ushort* h1b      = (ushort*)ws;   ws += (size_t)N * 64 * 2;
  float*  h2       = (float*)ws;    /* += N*64*4 */
  // total ~ 0.8 + 6.4 + 25.6 + 3.2 + 12.8 + 25.6 ~= 75 MB

  int nb = (N + CHUNK - 1) / CHUNK;

  hipMemsetAsync(deg, 0, (size_t)N * 4, stream);
  hist_kernel<<<(E + 255) / 256, 256, 0, stream>>>(dstIdx, deg, E);
  scan1_kernel<<<nb, 256, 0, stream>>>(deg, cursor, blockSum, N);
  scan2_kernel<<<1, 64, 0, stream>>>(blockSum, blockOff, nb);
  scan3_kernel<<<(N + 255) / 256, 256, 0, stream>>>(cursor, blockOff, N);
  scatter_kernel<<<(E + 255) / 256, 256, 0, stream>>>(srcIdx, dstIdx, ea,
                                                      cursor, csr_src, csr_ea, E);
  conv1_gather_kernel<<<(N + 255) / 256, 256, 0, stream>>>(
      x, csr_ea, csr_src, We1, be1, deg, cursor, agg1, N);
  mlp1_kernel<<<2048, 256, 0, stream>>>(x, agg1, W1a, b1a, W1b, b1b, h1b, N);
  conv2_mlp2_kernel<<<2048, 256, 0, stream>>>(h1b, csr_ea, csr_src, deg,
                                              cursor, We2, be2, W2a, b2a, W2b,
                                              b2b, h2, N);
  pool_fc_kernel<<<G, 64, 0, stream>>>(h2, batch, Wfc, bfc, (float*)d_out, N, G);
}